// Round 6
// baseline (312.476 us; speedup 1.0000x reference)
//
#include <hip/hip_runtime.h>

typedef __bf16 bf16_t;
typedef __bf16 bf16x8 __attribute__((ext_vector_type(8)));
typedef __bf16 bf16x4 __attribute__((ext_vector_type(4)));
typedef __bf16 bf16x2 __attribute__((ext_vector_type(2)));
typedef float  f32x4  __attribute__((ext_vector_type(4)));

#define MFMA16(a,b,c) __builtin_amdgcn_mfma_f32_16x16x32_bf16((a),(b),(c),0,0,0)

// ---- constants (problem is fixed-shape) ----
#define BB 8
#define NN 2048
#define CC 128
#define CIN 64
#define KNB 16            // neighbors
#define BNT (BB*NN)       // 16384 points

// XCD affinity: batch a block touches == blockIdx%8 == its XCD (R6-verified).
static __device__ __forceinline__ int remap256(int x) { return ((x & 7) << 5) | (x >> 3); }

static __device__ __forceinline__ bf16x8 cvt8(const float* src) {
  f32x4 a0 = *(const f32x4*)src;
  f32x4 a1 = *(const f32x4*)(src + 4);
  bf16x8 fr;
  fr[0] = (__bf16)a0[0]; fr[1] = (__bf16)a0[1]; fr[2] = (__bf16)a0[2]; fr[3] = (__bf16)a0[3];
  fr[4] = (__bf16)a1[0]; fr[5] = (__bf16)a1[1]; fr[6] = (__bf16)a1[2]; fr[7] = (__bf16)a1[3];
  return fr;
}

// ============================================================
// Kernel 1: in_proj + LN1 (R6-proven body; h stored bf16) with
// weight side-work fused in (blocks >= 256, no LDS use):
//   - bf16 conversions: Wv, Wd2, Wf1, Wf2
//   - Wa-folded products (bf16): Wqa = Wa@Wq, Wka = Wa@Wk, Wd2a = Wa@Wd2
//   - bd2a = Wa@bd2 (f32)
// ============================================================
__global__ __launch_bounds__(256) void inproj_compw_k(
    const float* __restrict__ x, const float* __restrict__ Win, const float* __restrict__ bin,
    const float* __restrict__ g1, const float* __restrict__ b1,
    bf16_t* __restrict__ hb, bf16_t* __restrict__ hnb,
    const float* __restrict__ Wq, const float* __restrict__ Wk, const float* __restrict__ Wv,
    const float* __restrict__ Wd2, const float* __restrict__ Wa,
    const float* __restrict__ Wf1, const float* __restrict__ Wf2, const float* __restrict__ bd2,
    bf16_t* __restrict__ Wqab, bf16_t* __restrict__ Wkab, bf16_t* __restrict__ Wvb,
    bf16_t* __restrict__ Wd2b, bf16_t* __restrict__ Wd2ab,
    bf16_t* __restrict__ Wf1b, bf16_t* __restrict__ Wf2b, float* __restrict__ bd2a) {
  __shared__ bf16_t As[64 * 72];
  __shared__ bf16_t Bs[128 * 72];
  __shared__ float hs[64 * 132];
  int t = threadIdx.x;
  if (blockIdx.x >= 256) {
    int bi = blockIdx.x - 256;
    if (bi < 32) {           // plain bf16 casts, RNE
      int mat = bi >> 3, xi = bi & 7;
      int nel = (mat >= 2) ? 65536 : 16384;
      const float* S = mat == 0 ? Wv : mat == 1 ? Wd2 : mat == 2 ? Wf1 : Wf2;
      bf16_t* D = mat == 0 ? Wvb : mat == 1 ? Wd2b : mat == 2 ? Wf1b : Wf2b;
      for (int i = xi * 256 + t; i * 8 < nel; i += 2048)
        *(bf16x8*)(D + i * 8) = cvt8(S + i * 8);
    } else if (bi < 80) {    // Wa-folded products: D[c,i] = sum_e Wa[c,e]*R[e,i]
      int pi = bi - 32, mat = pi >> 4, xi = pi & 15;
      const float* R = mat == 0 ? Wq : mat == 1 ? Wk : Wd2;
      bf16_t* D = mat == 0 ? Wqab : mat == 1 ? Wkab : Wd2ab;
      int c = xi * 8 + (t >> 5);
      int i0 = (t & 31) * 4;
      const float* war = Wa + (size_t)c * CC;
      f32x4 acc = {0.f, 0.f, 0.f, 0.f};
      #pragma unroll 4
      for (int e = 0; e < CC; ++e) {
        float a = war[e];
        f32x4 bq = *(const f32x4*)(R + (size_t)e * CC + i0);
        acc[0] = fmaf(a, bq[0], acc[0]);
        acc[1] = fmaf(a, bq[1], acc[1]);
        acc[2] = fmaf(a, bq[2], acc[2]);
        acc[3] = fmaf(a, bq[3], acc[3]);
      }
      bf16x4 o;
      o[0] = (__bf16)acc[0]; o[1] = (__bf16)acc[1];
      o[2] = (__bf16)acc[2]; o[3] = (__bf16)acc[3];
      *(bf16x4*)(D + (size_t)c * CC + i0) = o;
    } else {                 // bd2a[c] = sum_e Wa[c,e]*bd2[e]
      if (t < 128) {
        float s = 0.f;
        const float* war = Wa + (size_t)t * CC;
        #pragma unroll 4
        for (int e = 0; e < CC; ++e) s = fmaf(war[e], bd2[e], s);
        bd2a[t] = s;
      }
    }
    return;
  }
  int lane = t & 63, w = t >> 6, quad = lane >> 4, l15 = lane & 15;
  int mBase = remap256(blockIdx.x) * 64;
  int b = mBase >> 11, n0 = mBase & (NN - 1);
  const float* xb = x + (size_t)b * CIN * NN;
  {
    int k = t >> 2, part = t & 3;
    #pragma unroll
    for (int i = 0; i < 4; ++i) {
      f32x4 v = *(const f32x4*)(xb + (size_t)k * NN + n0 + part * 16 + i * 4);
      #pragma unroll
      for (int j2 = 0; j2 < 4; ++j2) As[(part * 16 + i * 4 + j2) * 72 + k] = (__bf16)v[j2];
    }
  }
  {
    int row = t >> 1, seg = (t & 1) * 32;
    #pragma unroll
    for (int i = 0; i < 4; ++i)
      *(bf16x8*)(&Bs[row * 72 + seg + i * 8]) = cvt8(Win + (size_t)row * CIN + seg + i * 8);
  }
  __syncthreads();
  f32x4 acc[2][4] = {};
  #pragma unroll
  for (int s = 0; s < 2; ++s) {
    bf16x8 af[4];
    #pragma unroll
    for (int mt = 0; mt < 4; ++mt)
      af[mt] = *(const bf16x8*)(&As[(mt * 16 + l15) * 72 + s * 32 + quad * 8]);
    #pragma unroll
    for (int t2 = 0; t2 < 2; ++t2) {
      bf16x8 bfr = *(const bf16x8*)(&Bs[((w * 2 + t2) * 16 + l15) * 72 + s * 32 + quad * 8]);
      #pragma unroll
      for (int mt = 0; mt < 4; ++mt) acc[t2][mt] = MFMA16(af[mt], bfr, acc[t2][mt]);
    }
  }
  #pragma unroll
  for (int t2 = 0; t2 < 2; ++t2) {
    int col = (w * 2 + t2) * 16 + l15;
    float bv = bin[col];
    #pragma unroll
    for (int mt = 0; mt < 4; ++mt)
      #pragma unroll
      for (int reg = 0; reg < 4; ++reg)
        hs[(mt * 16 + quad * 4 + reg) * 132 + col] = acc[t2][mt][reg] + bv;
  }
  __syncthreads();
  {
    int row = t >> 2, c0 = (t & 3) * 32;
    float v[32];
    #pragma unroll
    for (int i = 0; i < 8; ++i) *(f32x4*)(v + i * 4) = *(const f32x4*)(&hs[row * 132 + c0 + i * 4]);
    float s1 = 0.f, s2 = 0.f;
    #pragma unroll
    for (int i = 0; i < 32; ++i) { s1 += v[i]; s2 += v[i] * v[i]; }
    s1 += __shfl_xor(s1, 1); s1 += __shfl_xor(s1, 2);
    s2 += __shfl_xor(s2, 1); s2 += __shfl_xor(s2, 2);
    float mu = s1 * (1.f / CC);
    float var = s2 * (1.f / CC) - mu * mu;
    float rs = rsqrtf(var + 1e-5f);
    bf16_t* hrow = hb + (size_t)(mBase + row) * CC + c0;
    #pragma unroll
    for (int i = 0; i < 4; ++i) {
      bf16x8 ho;
      #pragma unroll
      for (int j = 0; j < 8; ++j) ho[j] = (__bf16)v[i * 8 + j];
      *(bf16x8*)(hrow + i * 8) = ho;
    }
    bf16_t* hnrow = hnb + (size_t)(mBase + row) * CC + c0;
    #pragma unroll
    for (int i = 0; i < 4; ++i) {
      f32x4 g4a = ((const f32x4*)g1)[(c0 >> 2) + i * 2],     g4b = ((const f32x4*)g1)[(c0 >> 2) + i * 2 + 1];
      f32x4 b4a = ((const f32x4*)b1)[(c0 >> 2) + i * 2],     b4b = ((const f32x4*)b1)[(c0 >> 2) + i * 2 + 1];
      bf16x8 o;
      #pragma unroll
      for (int j = 0; j < 4; ++j) o[j]     = (__bf16)((v[i * 8 + j]     - mu) * rs * g4a[j] + b4a[j]);
      #pragma unroll
      for (int j = 0; j < 4; ++j) o[4 + j] = (__bf16)((v[i * 8 + 4 + j] - mu) * rs * g4b[j] + b4b[j]);
      *(bf16x8*)(hnrow + i * 8) = o;
    }
  }
}

// ============================================================
// KNN body (R6 verbatim, LDS passed in).
// ============================================================
static __device__ __forceinline__ void cas(double& a, double& b) {
  double lo = fmin(a, b), hi = fmax(a, b); a = lo; b = hi;
}
#define S8(K,o) \
  cas(K[o+0],K[o+1]); cas(K[o+2],K[o+3]); cas(K[o+4],K[o+5]); cas(K[o+6],K[o+7]); \
  cas(K[o+0],K[o+2]); cas(K[o+1],K[o+3]); cas(K[o+4],K[o+6]); cas(K[o+5],K[o+7]); \
  cas(K[o+1],K[o+2]); cas(K[o+5],K[o+6]); \
  cas(K[o+0],K[o+4]); cas(K[o+1],K[o+5]); cas(K[o+2],K[o+6]); cas(K[o+3],K[o+7]); \
  cas(K[o+2],K[o+4]); cas(K[o+3],K[o+5]); \
  cas(K[o+1],K[o+2]); cas(K[o+3],K[o+4]); cas(K[o+5],K[o+6]);
#define M8(K,a,b) \
  K[a+0]=fmin(K[a+0],K[b+7]); K[a+1]=fmin(K[a+1],K[b+6]); K[a+2]=fmin(K[a+2],K[b+5]); K[a+3]=fmin(K[a+3],K[b+4]); \
  K[a+4]=fmin(K[a+4],K[b+3]); K[a+5]=fmin(K[a+5],K[b+2]); K[a+6]=fmin(K[a+6],K[b+1]); K[a+7]=fmin(K[a+7],K[b+0]); \
  cas(K[a+0],K[a+4]); cas(K[a+1],K[a+5]); cas(K[a+2],K[a+6]); cas(K[a+3],K[a+7]); \
  cas(K[a+0],K[a+2]); cas(K[a+1],K[a+3]); cas(K[a+4],K[a+6]); cas(K[a+5],K[a+7]); \
  cas(K[a+0],K[a+1]); cas(K[a+2],K[a+3]); cas(K[a+4],K[a+5]); cas(K[a+6],K[a+7]);

static __device__ void knn_impl(float* sp, const float* __restrict__ p,
                                int* __restrict__ idxo, int bid) {
  float* px = sp; float* py = sp + NN; float* pz = sp + 2 * NN;
  int t = threadIdx.x;
  int b = bid >> 9;
  int g = bid & 511;
  const float* pb = p + (size_t)b * 3 * NN;
  for (int i = t; i < NN; i += 256) { px[i] = pb[i]; py[i] = pb[NN + i]; pz[i] = pb[2 * NN + i]; }
  __syncthreads();
  int w = t >> 6, lane = t & 63;
  int n = g * 4 + w;
  float pnx = px[n], pny = py[n], pnz = pz[n];
  double key[32];
  #pragma unroll
  for (int s = 0; s < 32; ++s) {
    int m = s * 64 + lane;
    float dx = pnx - px[m], dy = pny - py[m], dz = pnz - pz[m];
    float dist = dx * dx + dy * dy + dz * dz;
    unsigned db = (m == n) ? 0x7F800000u : __float_as_uint(dist);
    key[s] = __hiloint2double((int)db, m);
  }
  S8(key, 0); S8(key, 8); S8(key, 16); S8(key, 24);
  M8(key, 0, 8); M8(key, 16, 24); M8(key, 0, 16);
  const double DINF = __hiloint2double(0x7F900000, 0);
  int* myout = idxo + ((size_t)b * NN + n) * KNB;
  #pragma unroll 1
  for (int r = 0; r < 16; ++r) {
    double gm = key[0];
    #pragma unroll
    for (int off = 1; off < 64; off <<= 1) {
      double o = __shfl_xor(gm, off);
      gm = fmin(gm, o);
    }
    if (lane == 0) myout[r] = __double2loint(gm);
    bool win = (key[0] == gm);
    key[0] = win ? key[1] : key[0];
    key[1] = win ? key[2] : key[1];
    key[2] = win ? key[3] : key[2];
    key[3] = win ? key[4] : key[3];
    key[4] = win ? key[5] : key[4];
    key[5] = win ? key[6] : key[5];
    key[6] = win ? key[7] : key[6];
    key[7] = win ? DINF   : key[7];
  }
}

// ============================================================
// 64x64 GEMM body, BK=32, A & W bf16 (pre-converted).
// EPI: 1 relu->bf16, 2 +resid(bf16) transposed fp32 [B,C,N], 3 bf16,
//      4 plain f32 row-major (full-precision ka for attn logits).
// ============================================================
template<int EPI>
static __device__ void gemm_body(bf16_t* As, bf16_t* Bs,
    const bf16_t* __restrict__ Ab, const bf16_t* __restrict__ Wb, const float* __restrict__ bias,
    float* __restrict__ outF, bf16_t* __restrict__ outB, const bf16_t* __restrict__ resid,
    int mBase, int nBase, int Ncol, int Kdim) {
  int t = threadIdx.x;
  int lane = t & 63, w = t >> 6, quad = lane >> 4, l15 = lane & 15;
  int r = t >> 2, seg = (t & 3) * 8;
  f32x4 acc[4] = {{0,0,0,0},{0,0,0,0},{0,0,0,0},{0,0,0,0}};
  for (int k0 = 0; k0 < Kdim; k0 += 32) {
    __syncthreads();
    *(bf16x8*)(&As[r * 40 + seg]) = *(const bf16x8*)(Ab + (size_t)(mBase + r) * Kdim + k0 + seg);
    *(bf16x8*)(&Bs[r * 40 + seg]) = *(const bf16x8*)(Wb + (size_t)(nBase + r) * Kdim + k0 + seg);
    __syncthreads();
    bf16x8 bfr = *(const bf16x8*)(&Bs[(w * 16 + l15) * 40 + quad * 8]);
    #pragma unroll
    for (int mt = 0; mt < 4; ++mt) {
      bf16x8 afr = *(const bf16x8*)(&As[(mt * 16 + l15) * 40 + quad * 8]);
      acc[mt] = MFMA16(afr, bfr, acc[mt]);
    }
  }
  int n = nBase + w * 16 + l15;
  float bv = bias ? bias[n] : 0.f;
  #pragma unroll
  for (int mt = 0; mt < 4; ++mt) {
    #pragma unroll
    for (int reg = 0; reg < 4; ++reg) {
      int m = mBase + mt * 16 + quad * 4 + reg;
      float val = acc[mt][reg] + bv;
      if (EPI == 1) {
        outB[(size_t)m * Ncol + n] = (__bf16)fmaxf(val, 0.f);
      } else if (EPI == 3) {
        outB[(size_t)m * Ncol + n] = (__bf16)val;
      } else if (EPI == 4) {
        outF[(size_t)m * Ncol + n] = val;
      } else {
        val += (float)resid[(size_t)m * CC + n];
        int bo = m >> 11, np = m & (NN - 1);
        outF[((size_t)bo * CC + n) * NN + np] = val;
      }
    }
  }
}

template<int EPI>
__global__ __launch_bounds__(256) void gemm_k(
    const bf16_t* __restrict__ Ab, const bf16_t* __restrict__ Wb, const float* __restrict__ bias,
    float* __restrict__ outF, bf16_t* __restrict__ outB, const bf16_t* __restrict__ resid,
    int Ncol, int Kdim) {
  __shared__ bf16_t As[64 * 40];
  __shared__ bf16_t Bs[64 * 40];
  gemm_body<EPI>(As, Bs, Ab, Wb, bias, outF, outB, resid,
                 remap256(blockIdx.x) * 64, blockIdx.y * 64, Ncol, Kdim);
}

// ============================================================
// Fused knn + qkv dispatch. Computes
//   qa = hn@(Wa@Wq)^T (bf16 — its rounding is CONSTANT across the
//        softmax axis j, so it cancels exactly in softmax)
//   ka = hn@(Wa@Wk)^T (f32 — varies per neighbor, rounding matters)
//   v  = hn@Wv^T (bf16)
// ============================================================
__global__ __launch_bounds__(256) void knn_qkv_k(
    const float* __restrict__ p, int* __restrict__ idxo,
    const bf16_t* __restrict__ hnb,
    const bf16_t* __restrict__ Wqab, const bf16_t* __restrict__ Wkab, const bf16_t* __restrict__ Wvb,
    bf16_t* __restrict__ qb, float* __restrict__ kb, bf16_t* __restrict__ vb) {
  __shared__ __align__(16) char smem[3 * NN * 4];   // 24576 B
  if (blockIdx.x < 4096) {
    knn_impl((float*)smem, p, idxo, blockIdx.x);
  } else {
    bf16_t* As = (bf16_t*)smem;
    bf16_t* Bs = As + 64 * 40;
    int bx = blockIdx.x - 4096;
    int yy = bx >> 8, xx = bx & 255;
    int sel = yy >> 1;
    int mB = remap256(xx) * 64, nB = (yy & 1) * 64;
    if (sel == 0)      gemm_body<3>(As, Bs, hnb, Wqab, nullptr, nullptr, qb, nullptr, mB, nB, CC, CC);
    else if (sel == 1) gemm_body<4>(As, Bs, hnb, Wkab, nullptr, kb, nullptr, nullptr, mB, nB, CC, CC);
    else               gemm_body<3>(As, Bs, hnb, Wvb, nullptr, nullptr, vb, nullptr, mB, nB, CC, CC);
  }
}

// ============================================================
// Kernel 5: fused neighbor attention, Wa-folded form.
//   u   = relu(rel@Wd1^T + bd1)           (cooperative, LDS, bf16)
//   da  = u @ Wd2a^T                      (MFMA pass A)
//   lv  = da + qa - ka + (bd2a + ba)      (ka f32; qa bf16 cancels in softmax)
//   d0  = u @ Wd2^T                       (MFMA pass D; bd2 folded at end)
//   y   = softmax_j(lv) . (v + d0) + bd2
// launch_bounds (256,3) — R2 proved (256,5) => spill cliff.
// ============================================================
__global__ __launch_bounds__(256, 3) void attn_k(
    const bf16_t* __restrict__ qbuf, const float* __restrict__ kbuf, const bf16_t* __restrict__ vbuf,
    const float* __restrict__ p, const int* __restrict__ idx,
    const float* __restrict__ Wd1, const float* __restrict__ bd1,
    const bf16_t* __restrict__ Wd2b, const float* __restrict__ bd2,
    const bf16_t* __restrict__ Wd2ab, const float* __restrict__ bd2a,
    const float* __restrict__ ba,
    const float* __restrict__ g2, const float* __restrict__ b2,
    const bf16_t* __restrict__ hb, bf16_t* __restrict__ hresb, bf16_t* __restrict__ h2) {
  __shared__ bf16_t ts[64 * 136];      // u matrix (bf16, padded stride)
  __shared__ float hrs[4 * 128];
  __shared__ f32x4 wd1s[128];          // {Wd1[c][0..2], bd1[c]}
  __shared__ f32x4 rels4[64];          // {rx,ry,rz,0}
  __shared__ int idxs[64];             // pre-scaled: (batch*NN+jj)*CC
  int t = threadIdx.x;
  int lane = t & 63, w = t >> 6, quad = lane >> 4, l15 = lane & 15;
  int batch = blockIdx.x & 7, grp = blockIdx.x >> 3;
  int bn0 = batch * NN + grp * 4;
  const float* pb = p + (size_t)batch * 3 * NN;
  int col0 = w * 32 + l15;
  int col1 = col0 + 16;

  if (t < 64) {
    int jj = idx[(size_t)bn0 * KNB + t];
    idxs[t] = (batch * NN + jj) * CC;
    int npt = grp * 4 + (t >> 4);
    f32x4 rv;
    rv[0] = pb[npt]          - pb[jj];
    rv[1] = pb[NN + npt]     - pb[NN + jj];
    rv[2] = pb[2 * NN + npt] - pb[2 * NN + jj];
    rv[3] = 0.f;
    rels4[t] = rv;
  }
  if (t < 128) {
    f32x4 wv;
    wv[0] = Wd1[t * 3]; wv[1] = Wd1[t * 3 + 1]; wv[2] = Wd1[t * 3 + 2]; wv[3] = bd1[t];
    wd1s[t] = wv;
  }
  __syncthreads();

  // cooperative u: each thread computes one row-quarter (32 channels)
  {
    int row = t >> 2, cseg = (t & 3) * 32;
    f32x4 rv = rels4[row];
    #pragma unroll
    for (int i = 0; i < 4; ++i) {
      bf16x8 u8;
      #pragma unroll
      for (int j = 0; j < 8; ++j) {
        f32x4 wv = wd1s[cseg + i * 8 + j];
        float tv = fmaf(wv[0], rv[0], fmaf(wv[1], rv[1], fmaf(wv[2], rv[2], wv[3])));
        u8[j] = (__bf16)fmaxf(tv, 0.f);
      }
      *(bf16x8*)(&ts[row * 136 + cseg + i * 8]) = u8;
    }
  }
  __syncthreads();

  // issue qa/ka gathers early — latency hides under pass-A MFMAs
  float qv[2][4];
  #pragma unroll
  for (int mt = 0; mt < 4; ++mt) {
    qv[0][mt] = (float)qbuf[(size_t)(bn0 + mt) * CC + col0];
    qv[1][mt] = (float)qbuf[(size_t)(bn0 + mt) * CC + col1];
  }
  float kreg[2][4][4];
  #pragma unroll
  for (int mt = 0; mt < 4; ++mt)
    #pragma unroll
    for (int reg = 0; reg < 4; ++reg) {
      size_t base = (size_t)idxs[mt * 16 + quad * 4 + reg];
      kreg[0][mt][reg] = kbuf[base + col0];
      kreg[1][mt][reg] = kbuf[base + col1];
    }

  // pass A: acca = u @ Wd2a^T
  f32x4 acca[2][4] = {};
  {
    bf16x8 Bf[2][4];
    #pragma unroll
    for (int t2 = 0; t2 < 2; ++t2) {
      int row = w * 32 + t2 * 16 + l15;
      #pragma unroll
      for (int s = 0; s < 4; ++s)
        Bf[t2][s] = *(const bf16x8*)(Wd2ab + (size_t)row * CC + s * 32 + quad * 8);
    }
    #pragma unroll
    for (int s = 0; s < 4; ++s) {
      bf16x8 af[4];
      #pragma unroll
      for (int mt = 0; mt < 4; ++mt)
        af[mt] = *(const bf16x8*)(&ts[(mt * 16 + l15) * 136 + s * 32 + quad * 8]);
      #pragma unroll
      for (int t2 = 0; t2 < 2; ++t2)
        #pragma unroll
        for (int mt = 0; mt < 4; ++mt)
          acca[t2][mt] = MFMA16(af[mt], Bf[t2][s], acca[t2][mt]);
    }
  }

  // combine logits into acca (frees kreg/qv before pass D)
  #pragma unroll
  for (int t2 = 0; t2 < 2; ++t2) {
    int col = t2 ? col1 : col0;
    float cA = bd2a[col] + ba[col];
    #pragma unroll
    for (int mt = 0; mt < 4; ++mt)
      #pragma unroll
      for (int reg = 0; reg < 4; ++reg)
        acca[t2][mt][reg] += qv[t2][mt] - kreg[t2][mt][reg] + cA;
  }

  // issue v/h gathers early — latency hides under pass-D MFMAs
  float vreg[2][4][4];
  #pragma unroll
  for (int mt = 0; mt < 4; ++mt)
    #pragma unroll
    for (int reg = 0; reg < 4; ++reg) {
      size_t base = (size_t)idxs[mt * 16 + quad * 4 + reg];
      vreg[0][mt][reg] = (float)vbuf[base + col0];
      vreg[1][mt][reg] = (float)vbuf[base + col1];
    }
  float hv[2][4];
  if (quad == 0) {
    #pragma unroll
    for (int mt = 0; mt < 4; ++mt) {
      hv[0][mt] = (float)hb[(size_t)(bn0 + mt) * CC + col0];
      hv[1][mt] = (float)hb[(size_t)(bn0 + mt) * CC + col1];
    }
  }

  // pass D: accd = u @ Wd2^T (no bias; bd2 folded into output)
  f32x4 accd[2][4] = {};
  {
    bf16x8 Bf[2][4];
    #pragma unroll
    for (int t2 = 0; t2 < 2; ++t2) {
      int row = w * 32 + t2 * 16 + l15;
      #pragma unroll
      for (int s = 0; s < 4; ++s)
        Bf[t2][s] = *(const bf16x8*)(Wd2b + (size_t)row * CC + s * 32 + quad * 8);
    }
    #pragma unroll
    for (int s = 0; s < 4; ++s) {
      bf16x8 af[4];
      #pragma unroll
      for (int mt = 0; mt < 4; ++mt)
        af[mt] = *(const bf16x8*)(&ts[(mt * 16 + l15) * 136 + s * 32 + quad * 8]);
      #pragma unroll
      for (int t2 = 0; t2 < 2; ++t2)
        #pragma unroll
        for (int mt = 0; mt < 4; ++mt)
          accd[t2][mt] = MFMA16(af[mt], Bf[t2][s], accd[t2][mt]);
    }
  }

  // softmax over neighbors + weighted sum
  #pragma unroll
  for (int t2 = 0; t2 < 2; ++t2) {
    int col = t2 ? col1 : col0;
    float bv = bd2[col];
    #pragma unroll
    for (int mt = 0; mt < 4; ++mt) {
      float lv0 = acca[t2][mt][0], lv1 = acca[t2][mt][1];
      float lv2 = acca[t2][mt][2], lv3 = acca[t2][mt][3];
      float mx = fmaxf(fmaxf(lv0, lv1), fmaxf(lv2, lv3));
      mx = fmaxf(mx, __shfl_xor(mx, 16));
      mx = fmaxf(mx, __shfl_xor(mx, 32));
      float e0 = __expf(lv0 - mx), e1 = __expf(lv1 - mx);
      float e2 = __expf(lv2 - mx), e3 = __expf(lv3 - mx);
      float ss = e0 + e1 + e2 + e3;
      ss += __shfl_xor(ss, 16); ss += __shfl_xor(ss, 32);
      float yv = e0 * (vreg[t2][mt][0] + accd[t2][mt][0])
               + e1 * (vreg[t2][mt][1] + accd[t2][mt][1])
               + e2 * (vreg[t2][mt][2] + accd[t2][mt][2])
               + e3 * (vreg[t2][mt][3] + accd[t2][mt][3]);
      yv += __shfl_xor(yv, 16); yv += __shfl_xor(yv, 32);
      if (quad == 0) {
        float hvv = hv[t2][mt] + yv / ss + bv;   // + bd2[col]: sum(a)=1
        hresb[(size_t)(bn0 + mt) * CC + col] = (__bf16)hvv;
        hrs[mt * 128 + col] = hvv;
      }
    }
  }
  __syncthreads();

  {
    int c0 = lane * 2;
    float v0 = hrs[w * 128 + c0], v1 = hrs[w * 128 + c0 + 1];
    float s1 = v0 + v1, s2 = v0 * v0 + v1 * v1;
    #pragma unroll
    for (int off = 1; off < 64; off <<= 1) { s1 += __shfl_xor(s1, off); s2 += __shfl_xor(s2, off); }
    float mu = s1 * (1.f / CC);
    float var = s2 * (1.f / CC) - mu * mu;
    float rs = rsqrtf(var + 1e-5f);
    bf16x2 o;
    o[0] = (__bf16)((v0 - mu) * rs * g2[c0] + b2[c0]);
    o[1] = (__bf16)((v1 - mu) * rs * g2[c0 + 1] + b2[c0 + 1]);
    *(bf16x2*)(h2 + (size_t)(bn0 + w) * CC + c0) = o;
  }
}

// ============================================================
extern "C" void kernel_launch(void* const* d_in, const int* in_sizes, int n_in,
                              void* d_out, int out_size, void* d_ws, size_t ws_size,
                              hipStream_t stream) {
  const float* x   = (const float*)d_in[0];
  const float* p   = (const float*)d_in[1];
  const float* Win = (const float*)d_in[2];
  const float* bin = (const float*)d_in[3];
  const float* Wq  = (const float*)d_in[4];
  const float* Wk  = (const float*)d_in[5];
  const float* Wv  = (const float*)d_in[6];
  const float* Wd1 = (const float*)d_in[7];
  const float* bd1 = (const float*)d_in[8];
  const float* Wd2 = (const float*)d_in[9];
  const float* bd2 = (const float*)d_in[10];
  const float* Wa  = (const float*)d_in[11];
  const float* ba  = (const float*)d_in[12];
  const float* g1  = (const float*)d_in[13];
  const float* b1  = (const float*)d_in[14];
  const float* g2  = (const float*)d_in[15];
  const float* b2  = (const float*)d_in[16];
  const float* Wf1 = (const float*)d_in[17];
  const float* bf1 = (const float*)d_in[18];
  const float* Wf2 = (const float*)d_in[19];
  const float* bf2 = (const float*)d_in[20];
  float* out = (float*)d_out;

  // workspace (float offsets; SZ = BNT*CC = 2,097,152) — same 29.5 MB
  // footprint as the R0-proven layout:
  //  [0,SZ/2)        h bf16 (residual 1)
  //  [SZ/2,SZ)       hnb bf16 -> hres bf16 overlay (attn out, ffn2 resid)
  //  [SZ,1.5SZ)      qa bf16  }
  //  [1.5SZ,2.5SZ)   ka f32   } -> g bf16 overlays [SZ,3SZ) for FFN
  //  [2.5SZ,3SZ)     vb bf16  }
  //  [3SZ,3.5SZ)     h2 bf16
  //  [3.5SZ,3.625SZ) idx int[BNT*16]
  //  [3.625SZ,..)    bf16 weights (~0.43 MB) + bd2a f32
  const size_t SZ = (size_t)BNT * CC;
  float* wsf = (float*)d_ws;
  bf16_t* hb    = (bf16_t*)wsf;
  bf16_t* hnb   = (bf16_t*)(wsf + SZ / 2);
  bf16_t* hresb = hnb;
  bf16_t* qb    = (bf16_t*)(wsf + SZ);
  float*  kaf   = wsf + SZ + SZ / 2;
  bf16_t* vb    = (bf16_t*)(wsf + 2 * SZ + SZ / 2);
  bf16_t* g     = (bf16_t*)(wsf + SZ);         // overlay, live only after attn
  bf16_t* h2    = (bf16_t*)(wsf + 3 * SZ);
  int*    idxw  = (int*)(wsf + 3 * SZ + SZ / 2);
  bf16_t* Wqab  = (bf16_t*)(idxw + (size_t)BNT * KNB);
  bf16_t* Wkab  = Wqab  + 16384;
  bf16_t* Wvb   = Wkab  + 16384;
  bf16_t* Wd2b  = Wvb   + 16384;
  bf16_t* Wd2ab = Wd2b  + 16384;
  bf16_t* Wf1b  = Wd2ab + 16384;
  bf16_t* Wf2b  = Wf1b  + 65536;
  float*  bd2a  = (float*)(Wf2b + 65536);

  inproj_compw_k<<<256 + 81, 256, 0, stream>>>(x, Win, bin, g1, b1, hb, hnb,
                                               Wq, Wk, Wv, Wd2, Wa, Wf1, Wf2, bd2,
                                               Wqab, Wkab, Wvb, Wd2b, Wd2ab, Wf1b, Wf2b, bd2a);
  knn_qkv_k<<<4096 + 1536, 256, 0, stream>>>(p, idxw, hnb, Wqab, Wkab, Wvb, qb, kaf, vb);
  attn_k<<<BNT / 4, 256, 0, stream>>>(qb, kaf, vb, p, idxw, Wd1, bd1, Wd2b, bd2, Wd2ab, bd2a,
                                      ba, g2, b2, hb, hresb, h2);
  gemm_k<1><<<dim3(BNT / 64, 8), 256, 0, stream>>>(h2, Wf1b, bf1, nullptr, g, nullptr, 4 * CC, CC);
  gemm_k<2><<<dim3(BNT / 64, 2), 256, 0, stream>>>(g, Wf2b, bf2, out, nullptr, hresb, CC, 4 * CC);
}

// Round 7
// 260.638 us; speedup vs baseline: 1.1989x; 1.1989x over previous
//
#include <hip/hip_runtime.h>

typedef __bf16 bf16_t;
typedef __bf16 bf16x8 __attribute__((ext_vector_type(8)));
typedef __bf16 bf16x2 __attribute__((ext_vector_type(2)));
typedef float  f32x4  __attribute__((ext_vector_type(4)));

#define MFMA16(a,b,c) __builtin_amdgcn_mfma_f32_16x16x32_bf16((a),(b),(c),0,0,0)

// ---- constants (problem is fixed-shape) ----
#define BB 8
#define NN 2048
#define CC 128
#define CIN 64
#define KNB 16            // neighbors
#define BNT (BB*NN)       // 16384 points

// XCD affinity: batch a block touches == blockIdx%8 == its XCD (R6-verified).
static __device__ __forceinline__ int remap256(int x) { return ((x & 7) << 5) | (x >> 3); }

static __device__ __forceinline__ bf16x8 cvt8(const float* src) {
  f32x4 a0 = *(const f32x4*)src;
  f32x4 a1 = *(const f32x4*)(src + 4);
  bf16x8 fr;
  fr[0] = (__bf16)a0[0]; fr[1] = (__bf16)a0[1]; fr[2] = (__bf16)a0[2]; fr[3] = (__bf16)a0[3];
  fr[4] = (__bf16)a1[0]; fr[5] = (__bf16)a1[1]; fr[6] = (__bf16)a1[2]; fr[7] = (__bf16)a1[3];
  return fr;
}

// ============================================================
// Kernel 1: in_proj + LN1 (R6-proven body; h stored bf16) with the
// weight-conversion blocks FUSED in (blocks 256..311, no LDS use).
// ============================================================
__global__ __launch_bounds__(256) void inproj_compw_k(
    const float* __restrict__ x, const float* __restrict__ Win, const float* __restrict__ bin,
    const float* __restrict__ g1, const float* __restrict__ b1,
    bf16_t* __restrict__ hb, bf16_t* __restrict__ hnb,
    const float* __restrict__ Wq, const float* __restrict__ Wk, const float* __restrict__ Wv,
    const float* __restrict__ Wd2, const float* __restrict__ Wa,
    const float* __restrict__ Wf1, const float* __restrict__ Wf2,
    bf16_t* __restrict__ Wqb, bf16_t* __restrict__ Wkb, bf16_t* __restrict__ Wvb,
    bf16_t* __restrict__ Wd2b, bf16_t* __restrict__ Wab,
    bf16_t* __restrict__ Wf1b, bf16_t* __restrict__ Wf2b) {
  __shared__ bf16_t As[64 * 72];
  __shared__ bf16_t Bs[128 * 72];
  __shared__ float hs[64 * 132];
  int t = threadIdx.x;
  if (blockIdx.x >= 256) {   // weight-conversion blocks (plain bf16 casts, RNE)
    int bi = blockIdx.x - 256;
    int mat = bi >> 3, xi = bi & 7;
    int nel = (mat >= 5) ? 65536 : 16384;
    const float* S = mat == 0 ? Wq : mat == 1 ? Wk : mat == 2 ? Wv : mat == 3 ? Wd2
                   : mat == 4 ? Wa : mat == 5 ? Wf1 : Wf2;
    bf16_t* D = mat == 0 ? Wqb : mat == 1 ? Wkb : mat == 2 ? Wvb : mat == 3 ? Wd2b
              : mat == 4 ? Wab : mat == 5 ? Wf1b : Wf2b;
    for (int i = xi * 256 + t; i * 8 < nel; i += 2048)
      *(bf16x8*)(D + i * 8) = cvt8(S + i * 8);
    return;
  }
  int lane = t & 63, w = t >> 6, quad = lane >> 4, l15 = lane & 15;
  int mBase = remap256(blockIdx.x) * 64;
  int b = mBase >> 11, n0 = mBase & (NN - 1);
  const float* xb = x + (size_t)b * CIN * NN;
  {
    int k = t >> 2, part = t & 3;
    #pragma unroll
    for (int i = 0; i < 4; ++i) {
      f32x4 v = *(const f32x4*)(xb + (size_t)k * NN + n0 + part * 16 + i * 4);
      #pragma unroll
      for (int j2 = 0; j2 < 4; ++j2) As[(part * 16 + i * 4 + j2) * 72 + k] = (__bf16)v[j2];
    }
  }
  {
    int row = t >> 1, seg = (t & 1) * 32;
    #pragma unroll
    for (int i = 0; i < 4; ++i)
      *(bf16x8*)(&Bs[row * 72 + seg + i * 8]) = cvt8(Win + (size_t)row * CIN + seg + i * 8);
  }
  __syncthreads();
  f32x4 acc[2][4] = {};
  #pragma unroll
  for (int s = 0; s < 2; ++s) {
    bf16x8 af[4];
    #pragma unroll
    for (int mt = 0; mt < 4; ++mt)
      af[mt] = *(const bf16x8*)(&As[(mt * 16 + l15) * 72 + s * 32 + quad * 8]);
    #pragma unroll
    for (int t2 = 0; t2 < 2; ++t2) {
      bf16x8 bfr = *(const bf16x8*)(&Bs[((w * 2 + t2) * 16 + l15) * 72 + s * 32 + quad * 8]);
      #pragma unroll
      for (int mt = 0; mt < 4; ++mt) acc[t2][mt] = MFMA16(af[mt], bfr, acc[t2][mt]);
    }
  }
  #pragma unroll
  for (int t2 = 0; t2 < 2; ++t2) {
    int col = (w * 2 + t2) * 16 + l15;
    float bv = bin[col];
    #pragma unroll
    for (int mt = 0; mt < 4; ++mt)
      #pragma unroll
      for (int reg = 0; reg < 4; ++reg)
        hs[(mt * 16 + quad * 4 + reg) * 132 + col] = acc[t2][mt][reg] + bv;
  }
  __syncthreads();
  {
    int row = t >> 2, c0 = (t & 3) * 32;
    float v[32];
    #pragma unroll
    for (int i = 0; i < 8; ++i) *(f32x4*)(v + i * 4) = *(const f32x4*)(&hs[row * 132 + c0 + i * 4]);
    float s1 = 0.f, s2 = 0.f;
    #pragma unroll
    for (int i = 0; i < 32; ++i) { s1 += v[i]; s2 += v[i] * v[i]; }
    s1 += __shfl_xor(s1, 1); s1 += __shfl_xor(s1, 2);
    s2 += __shfl_xor(s2, 1); s2 += __shfl_xor(s2, 2);
    float mu = s1 * (1.f / CC);
    float var = s2 * (1.f / CC) - mu * mu;
    float rs = rsqrtf(var + 1e-5f);
    bf16_t* hrow = hb + (size_t)(mBase + row) * CC + c0;
    #pragma unroll
    for (int i = 0; i < 4; ++i) {
      bf16x8 ho;
      #pragma unroll
      for (int j = 0; j < 8; ++j) ho[j] = (__bf16)v[i * 8 + j];
      *(bf16x8*)(hrow + i * 8) = ho;
    }
    bf16_t* hnrow = hnb + (size_t)(mBase + row) * CC + c0;
    #pragma unroll
    for (int i = 0; i < 4; ++i) {
      f32x4 g4a = ((const f32x4*)g1)[(c0 >> 2) + i * 2],     g4b = ((const f32x4*)g1)[(c0 >> 2) + i * 2 + 1];
      f32x4 b4a = ((const f32x4*)b1)[(c0 >> 2) + i * 2],     b4b = ((const f32x4*)b1)[(c0 >> 2) + i * 2 + 1];
      bf16x8 o;
      #pragma unroll
      for (int j = 0; j < 4; ++j) o[j]     = (__bf16)((v[i * 8 + j]     - mu) * rs * g4a[j] + b4a[j]);
      #pragma unroll
      for (int j = 0; j < 4; ++j) o[4 + j] = (__bf16)((v[i * 8 + 4 + j] - mu) * rs * g4b[j] + b4b[j]);
      *(bf16x8*)(hnrow + i * 8) = o;
    }
  }
}

// ============================================================
// KNN body (R6 verbatim, LDS passed in).
// ============================================================
static __device__ __forceinline__ void cas(double& a, double& b) {
  double lo = fmin(a, b), hi = fmax(a, b); a = lo; b = hi;
}
#define S8(K,o) \
  cas(K[o+0],K[o+1]); cas(K[o+2],K[o+3]); cas(K[o+4],K[o+5]); cas(K[o+6],K[o+7]); \
  cas(K[o+0],K[o+2]); cas(K[o+1],K[o+3]); cas(K[o+4],K[o+6]); cas(K[o+5],K[o+7]); \
  cas(K[o+1],K[o+2]); cas(K[o+5],K[o+6]); \
  cas(K[o+0],K[o+4]); cas(K[o+1],K[o+5]); cas(K[o+2],K[o+6]); cas(K[o+3],K[o+7]); \
  cas(K[o+2],K[o+4]); cas(K[o+3],K[o+5]); \
  cas(K[o+1],K[o+2]); cas(K[o+3],K[o+4]); cas(K[o+5],K[o+6]);
#define M8(K,a,b) \
  K[a+0]=fmin(K[a+0],K[b+7]); K[a+1]=fmin(K[a+1],K[b+6]); K[a+2]=fmin(K[a+2],K[b+5]); K[a+3]=fmin(K[a+3],K[b+4]); \
  K[a+4]=fmin(K[a+4],K[b+3]); K[a+5]=fmin(K[a+5],K[b+2]); K[a+6]=fmin(K[a+6],K[b+1]); K[a+7]=fmin(K[a+7],K[b+0]); \
  cas(K[a+0],K[a+4]); cas(K[a+1],K[a+5]); cas(K[a+2],K[a+6]); cas(K[a+3],K[a+7]); \
  cas(K[a+0],K[a+2]); cas(K[a+1],K[a+3]); cas(K[a+4],K[a+6]); cas(K[a+5],K[a+7]); \
  cas(K[a+0],K[a+1]); cas(K[a+2],K[a+3]); cas(K[a+4],K[a+5]); cas(K[a+6],K[a+7]);

static __device__ void knn_impl(float* sp, const float* __restrict__ p,
                                int* __restrict__ idxo, int bid) {
  float* px = sp; float* py = sp + NN; float* pz = sp + 2 * NN;
  int t = threadIdx.x;
  int b = bid >> 9;
  int g = bid & 511;
  const float* pb = p + (size_t)b * 3 * NN;
  for (int i = t; i < NN; i += 256) { px[i] = pb[i]; py[i] = pb[NN + i]; pz[i] = pb[2 * NN + i]; }
  __syncthreads();
  int w = t >> 6, lane = t & 63;
  int n = g * 4 + w;
  float pnx = px[n], pny = py[n], pnz = pz[n];
  double key[32];
  #pragma unroll
  for (int s = 0; s < 32; ++s) {
    int m = s * 64 + lane;
    float dx = pnx - px[m], dy = pny - py[m], dz = pnz - pz[m];
    float dist = dx * dx + dy * dy + dz * dz;
    unsigned db = (m == n) ? 0x7F800000u : __float_as_uint(dist);
    key[s] = __hiloint2double((int)db, m);
  }
  S8(key, 0); S8(key, 8); S8(key, 16); S8(key, 24);
  M8(key, 0, 8); M8(key, 16, 24); M8(key, 0, 16);
  const double DINF = __hiloint2double(0x7F900000, 0);
  int* myout = idxo + ((size_t)b * NN + n) * KNB;
  #pragma unroll 1
  for (int r = 0; r < 16; ++r) {
    double gm = key[0];
    #pragma unroll
    for (int off = 1; off < 64; off <<= 1) {
      double o = __shfl_xor(gm, off);
      gm = fmin(gm, o);
    }
    if (lane == 0) myout[r] = __double2loint(gm);
    bool win = (key[0] == gm);
    key[0] = win ? key[1] : key[0];
    key[1] = win ? key[2] : key[1];
    key[2] = win ? key[3] : key[2];
    key[3] = win ? key[4] : key[3];
    key[4] = win ? key[5] : key[4];
    key[5] = win ? key[6] : key[5];
    key[6] = win ? key[7] : key[6];
    key[7] = win ? DINF   : key[7];
  }
}

// ============================================================
// 64x64 GEMM body, BK=32, A & W bf16 (pre-converted).
// EPI: 1 relu->bf16, 2 +resid(bf16) transposed fp32 [B,C,N], 3 bf16.
// ============================================================
template<int EPI>
static __device__ void gemm_body(bf16_t* As, bf16_t* Bs,
    const bf16_t* __restrict__ Ab, const bf16_t* __restrict__ Wb, const float* __restrict__ bias,
    float* __restrict__ outF, bf16_t* __restrict__ outB, const bf16_t* __restrict__ resid,
    int mBase, int nBase, int Ncol, int Kdim) {
  int t = threadIdx.x;
  int lane = t & 63, w = t >> 6, quad = lane >> 4, l15 = lane & 15;
  int r = t >> 2, seg = (t & 3) * 8;
  f32x4 acc[4] = {{0,0,0,0},{0,0,0,0},{0,0,0,0},{0,0,0,0}};
  for (int k0 = 0; k0 < Kdim; k0 += 32) {
    __syncthreads();
    *(bf16x8*)(&As[r * 40 + seg]) = *(const bf16x8*)(Ab + (size_t)(mBase + r) * Kdim + k0 + seg);
    *(bf16x8*)(&Bs[r * 40 + seg]) = *(const bf16x8*)(Wb + (size_t)(nBase + r) * Kdim + k0 + seg);
    __syncthreads();
    bf16x8 bfr = *(const bf16x8*)(&Bs[(w * 16 + l15) * 40 + quad * 8]);
    #pragma unroll
    for (int mt = 0; mt < 4; ++mt) {
      bf16x8 afr = *(const bf16x8*)(&As[(mt * 16 + l15) * 40 + quad * 8]);
      acc[mt] = MFMA16(afr, bfr, acc[mt]);
    }
  }
  int n = nBase + w * 16 + l15;
  float bv = bias ? bias[n] : 0.f;
  #pragma unroll
  for (int mt = 0; mt < 4; ++mt) {
    #pragma unroll
    for (int reg = 0; reg < 4; ++reg) {
      int m = mBase + mt * 16 + quad * 4 + reg;
      float val = acc[mt][reg] + bv;
      if (EPI == 1) {
        outB[(size_t)m * Ncol + n] = (__bf16)fmaxf(val, 0.f);
      } else if (EPI == 3) {
        outB[(size_t)m * Ncol + n] = (__bf16)val;
      } else {
        val += (float)resid[(size_t)m * CC + n];
        int bo = m >> 11, np = m & (NN - 1);
        outF[((size_t)bo * CC + n) * NN + np] = val;
      }
    }
  }
}

template<int EPI>
__global__ __launch_bounds__(256) void gemm_k(
    const bf16_t* __restrict__ Ab, const bf16_t* __restrict__ Wb, const float* __restrict__ bias,
    float* __restrict__ outF, bf16_t* __restrict__ outB, const bf16_t* __restrict__ resid,
    int Ncol, int Kdim) {
  __shared__ bf16_t As[64 * 40];
  __shared__ bf16_t Bs[64 * 40];
  gemm_body<EPI>(As, Bs, Ab, Wb, bias, outF, outB, resid,
                 remap256(blockIdx.x) * 64, blockIdx.y * 64, Ncol, Kdim);
}

// ============================================================
// Fused knn + qkv dispatch (R11/R13-proven). q = hn@Wq^T, k = hn@Wk^T,
// v = hn@Wv^T — all bf16 (R0 numerics; NO Wa-fold).
// ============================================================
__global__ __launch_bounds__(256) void knn_qkv_k(
    const float* __restrict__ p, int* __restrict__ idxo,
    const bf16_t* __restrict__ hnb,
    const bf16_t* __restrict__ Wqb, const bf16_t* __restrict__ Wkb, const bf16_t* __restrict__ Wvb,
    bf16_t* __restrict__ qb, bf16_t* __restrict__ kb, bf16_t* __restrict__ vb) {
  __shared__ __align__(16) char smem[3 * NN * 4];   // 24576 B
  if (blockIdx.x < 4096) {
    knn_impl((float*)smem, p, idxo, blockIdx.x);
  } else {
    bf16_t* As = (bf16_t*)smem;
    bf16_t* Bs = As + 64 * 40;
    int bx = blockIdx.x - 4096;
    int yy = bx >> 8, xx = bx & 255;
    int sel = yy >> 1;
    int mB = remap256(xx) * 64, nB = (yy & 1) * 64;
    if (sel == 0)      gemm_body<3>(As, Bs, hnb, Wqb, nullptr, nullptr, qb, nullptr, mB, nB, CC, CC);
    else if (sel == 1) gemm_body<3>(As, Bs, hnb, Wkb, nullptr, nullptr, kb, nullptr, mB, nB, CC, CC);
    else               gemm_body<3>(As, Bs, hnb, Wvb, nullptr, nullptr, vb, nullptr, mB, nB, CC, CC);
  }
}

// ============================================================
// Kernel 5: fused neighbor attention — R0 numerics EXACTLY (no fold),
// with ONE structural change: u = relu(rel@Wd1+bd1) is computed
// cooperatively ONCE into LDS (R0 computed it 4x redundantly, once per
// wave: 640 VALU ops/thread -> 160). Same fmaf chain per element, same
// bf16 rounding -> pass-D MFMA inputs are bit-identical to R0's af[].
// Everything downstream (ts = q-k+d, logits MFMA, softmax, LN2) is the
// R0 FP graph verbatim. idxs pre-scaled (integer-only change).
// ============================================================
__global__ __launch_bounds__(256, 3) void attn_k(
    const bf16_t* __restrict__ qbuf, const bf16_t* __restrict__ kbuf, const bf16_t* __restrict__ vbuf,
    const float* __restrict__ p, const int* __restrict__ idx,
    const float* __restrict__ Wd1, const float* __restrict__ bd1,
    const bf16_t* __restrict__ Wd2b, const float* __restrict__ bd2,
    const bf16_t* __restrict__ Wab, const float* __restrict__ ba,
    const float* __restrict__ g2, const float* __restrict__ b2,
    const bf16_t* __restrict__ hb, bf16_t* __restrict__ hresb, bf16_t* __restrict__ h2) {
  __shared__ bf16_t us[64 * 136];      // u matrix, computed once
  __shared__ bf16_t ts[64 * 136];      // q - k + d (logits MFMA input)
  __shared__ float hrs[4 * 128];
  __shared__ f32x4 wd1s[128];          // {Wd1[c][0..2], bd1[c]}
  __shared__ f32x4 rels4[64];          // {rx,ry,rz,0}
  __shared__ int idxs[64];             // pre-scaled: (batch*NN+jj)*CC
  int t = threadIdx.x;
  int lane = t & 63, w = t >> 6, quad = lane >> 4, l15 = lane & 15;
  int batch = blockIdx.x & 7, grp = blockIdx.x >> 3;
  int bn0 = batch * NN + grp * 4;
  const float* pb = p + (size_t)batch * 3 * NN;
  int col0 = w * 32 + l15;
  int col1 = col0 + 16;

  if (t < 64) {
    int jj = idx[(size_t)bn0 * KNB + t];
    idxs[t] = (batch * NN + jj) * CC;
    int npt = grp * 4 + (t >> 4);
    f32x4 rv;
    rv[0] = pb[npt]          - pb[jj];
    rv[1] = pb[NN + npt]     - pb[NN + jj];
    rv[2] = pb[2 * NN + npt] - pb[2 * NN + jj];
    rv[3] = 0.f;
    rels4[t] = rv;
  }
  if (t < 128) {
    f32x4 wv;
    wv[0] = Wd1[t * 3]; wv[1] = Wd1[t * 3 + 1]; wv[2] = Wd1[t * 3 + 2]; wv[3] = bd1[t];
    wd1s[t] = wv;
  }
  __syncthreads();

  // cooperative u: each thread computes one row-quarter (32 channels);
  // identical fmaf chain + bf16 rounding as R0's per-wave af[] compute.
  {
    int row = t >> 2, cseg = (t & 3) * 32;
    f32x4 rv = rels4[row];
    #pragma unroll
    for (int i = 0; i < 4; ++i) {
      bf16x8 u8;
      #pragma unroll
      for (int j = 0; j < 8; ++j) {
        f32x4 wv = wd1s[cseg + i * 8 + j];
        float tv = fmaf(wv[0], rv[0], fmaf(wv[1], rv[1], fmaf(wv[2], rv[2], wv[3])));
        u8[j] = (__bf16)fmaxf(tv, 0.f);
      }
      *(bf16x8*)(&us[row * 136 + cseg + i * 8]) = u8;
    }
  }
  __syncthreads();

  // q/k gathers issued before pass-D MFMAs (latency hides under MFMA)
  float qv[2][4];
  #pragma unroll
  for (int mt = 0; mt < 4; ++mt) {
    qv[0][mt] = (float)qbuf[(size_t)(bn0 + mt) * CC + col0];
    qv[1][mt] = (float)qbuf[(size_t)(bn0 + mt) * CC + col1];
  }
  float kreg[2][4][4];
  #pragma unroll
  for (int mt = 0; mt < 4; ++mt)
    #pragma unroll
    for (int reg = 0; reg < 4; ++reg) {
      size_t base = (size_t)idxs[mt * 16 + quad * 4 + reg];
      kreg[0][mt][reg] = (float)kbuf[base + col0];
      kreg[1][mt][reg] = (float)kbuf[base + col1];
    }

  // pass D: accd = u @ Wd2^T (fragments from LDS; values == R0's af)
  f32x4 accd[2][4] = {};
  {
    bf16x8 Bd[2][4];
    #pragma unroll
    for (int t2 = 0; t2 < 2; ++t2) {
      int row = w * 32 + t2 * 16 + l15;
      #pragma unroll
      for (int s = 0; s < 4; ++s)
        Bd[t2][s] = *(const bf16x8*)(Wd2b + (size_t)row * CC + s * 32 + quad * 8);
    }
    #pragma unroll
    for (int s = 0; s < 4; ++s) {
      bf16x8 af[4];
      #pragma unroll
      for (int mt = 0; mt < 4; ++mt)
        af[mt] = *(const bf16x8*)(&us[(mt * 16 + l15) * 136 + s * 32 + quad * 8]);
      #pragma unroll
      for (int t2 = 0; t2 < 2; ++t2)
        #pragma unroll
        for (int mt = 0; mt < 4; ++mt)
          accd[t2][mt] = MFMA16(af[mt], Bd[t2][s], accd[t2][mt]);
    }
  }

  // ts = q - k + d  (R0 formula verbatim; accd keeps the biased d)
  {
    float b2v0 = bd2[col0], b2v1 = bd2[col1];
    #pragma unroll
    for (int mt = 0; mt < 4; ++mt)
      #pragma unroll
      for (int reg = 0; reg < 4; ++reg) {
        int row = mt * 16 + quad * 4 + reg;
        float d0 = accd[0][mt][reg] + b2v0;
        float d1 = accd[1][mt][reg] + b2v1;
        accd[0][mt][reg] = d0;
        accd[1][mt][reg] = d1;
        ts[row * 136 + col0] = (__bf16)(qv[0][mt] - kreg[0][mt][reg] + d0);
        ts[row * 136 + col1] = (__bf16)(qv[1][mt] - kreg[1][mt][reg] + d1);
      }
  }
  __syncthreads();

  // v/h gathers issued before logits MFMAs
  float vreg[2][4][4];
  #pragma unroll
  for (int mt = 0; mt < 4; ++mt)
    #pragma unroll
    for (int reg = 0; reg < 4; ++reg) {
      size_t base = (size_t)idxs[mt * 16 + quad * 4 + reg];
      vreg[0][mt][reg] = (float)vbuf[base + col0];
      vreg[1][mt][reg] = (float)vbuf[base + col1];
    }
  float hv[2][4];
  if (quad == 0) {
    #pragma unroll
    for (int mt = 0; mt < 4; ++mt) {
      hv[0][mt] = (float)hb[(size_t)(bn0 + mt) * CC + col0];
      hv[1][mt] = (float)hb[(size_t)(bn0 + mt) * CC + col1];
    }
  }

  // logits MFMA: accl = ts @ Wa^T
  bf16x8 Ba[2][4];
  #pragma unroll
  for (int t2 = 0; t2 < 2; ++t2) {
    int row = w * 32 + t2 * 16 + l15;
    #pragma unroll
    for (int s = 0; s < 4; ++s)
      Ba[t2][s] = *(const bf16x8*)(Wab + (size_t)row * CC + s * 32 + quad * 8);
  }
  f32x4 accl[2][4] = {};
  #pragma unroll
  for (int s = 0; s < 4; ++s) {
    bf16x8 af[4];
    #pragma unroll
    for (int mt = 0; mt < 4; ++mt)
      af[mt] = *(const bf16x8*)(&ts[(mt * 16 + l15) * 136 + s * 32 + quad * 8]);
    #pragma unroll
    for (int t2 = 0; t2 < 2; ++t2)
      #pragma unroll
      for (int mt = 0; mt < 4; ++mt)
        accl[t2][mt] = MFMA16(af[mt], Ba[t2][s], accl[t2][mt]);
  }

  // softmax over neighbors + weighted sum (R0 verbatim)
  #pragma unroll
  for (int t2 = 0; t2 < 2; ++t2) {
    int col = t2 ? col1 : col0;
    float bav = ba[col];
    #pragma unroll
    for (int mt = 0; mt < 4; ++mt) {
      float lv0 = accl[t2][mt][0] + bav, lv1 = accl[t2][mt][1] + bav;
      float lv2 = accl[t2][mt][2] + bav, lv3 = accl[t2][mt][3] + bav;
      float mx = fmaxf(fmaxf(lv0, lv1), fmaxf(lv2, lv3));
      mx = fmaxf(mx, __shfl_xor(mx, 16));
      mx = fmaxf(mx, __shfl_xor(mx, 32));
      float e0 = __expf(lv0 - mx), e1 = __expf(lv1 - mx);
      float e2 = __expf(lv2 - mx), e3 = __expf(lv3 - mx);
      float ss = e0 + e1 + e2 + e3;
      ss += __shfl_xor(ss, 16); ss += __shfl_xor(ss, 32);
      float yv = e0 * (vreg[t2][mt][0] + accd[t2][mt][0])
               + e1 * (vreg[t2][mt][1] + accd[t2][mt][1])
               + e2 * (vreg[t2][mt][2] + accd[t2][mt][2])
               + e3 * (vreg[t2][mt][3] + accd[t2][mt][3]);
      yv += __shfl_xor(yv, 16); yv += __shfl_xor(yv, 32);
      if (quad == 0) {
        float hvv = hv[t2][mt] + yv / ss;
        hresb[(size_t)(bn0 + mt) * CC + col] = (__bf16)hvv;
        hrs[mt * 128 + col] = hvv;
      }
    }
  }
  __syncthreads();

  {
    int c0 = lane * 2;
    float v0 = hrs[w * 128 + c0], v1 = hrs[w * 128 + c0 + 1];
    float s1 = v0 + v1, s2 = v0 * v0 + v1 * v1;
    #pragma unroll
    for (int off = 1; off < 64; off <<= 1) { s1 += __shfl_xor(s1, off); s2 += __shfl_xor(s2, off); }
    float mu = s1 * (1.f / CC);
    float var = s2 * (1.f / CC) - mu * mu;
    float rs = rsqrtf(var + 1e-5f);
    bf16x2 o;
    o[0] = (__bf16)((v0 - mu) * rs * g2[c0] + b2[c0]);
    o[1] = (__bf16)((v1 - mu) * rs * g2[c0 + 1] + b2[c0 + 1]);
    *(bf16x2*)(h2 + (size_t)(bn0 + w) * CC + c0) = o;
  }
}

// ============================================================
extern "C" void kernel_launch(void* const* d_in, const int* in_sizes, int n_in,
                              void* d_out, int out_size, void* d_ws, size_t ws_size,
                              hipStream_t stream) {
  const float* x   = (const float*)d_in[0];
  const float* p   = (const float*)d_in[1];
  const float* Win = (const float*)d_in[2];
  const float* bin = (const float*)d_in[3];
  const float* Wq  = (const float*)d_in[4];
  const float* Wk  = (const float*)d_in[5];
  const float* Wv  = (const float*)d_in[6];
  const float* Wd1 = (const float*)d_in[7];
  const float* bd1 = (const float*)d_in[8];
  const float* Wd2 = (const float*)d_in[9];
  const float* bd2 = (const float*)d_in[10];
  const float* Wa  = (const float*)d_in[11];
  const float* ba  = (const float*)d_in[12];
  const float* g1  = (const float*)d_in[13];
  const float* b1  = (const float*)d_in[14];
  const float* g2  = (const float*)d_in[15];
  const float* b2  = (const float*)d_in[16];
  const float* Wf1 = (const float*)d_in[17];
  const float* bf1 = (const float*)d_in[18];
  const float* Wf2 = (const float*)d_in[19];
  const float* bf2 = (const float*)d_in[20];
  float* out = (float*)d_out;

  // workspace (float offsets; SZ = BNT*CC = 2,097,152) — R0 layout:
  //  [0,SZ/2)        h bf16 (residual 1)
  //  [SZ/2,SZ)       hnb bf16 -> hres bf16 overlay (attn out, ffn2 resid)
  //  [SZ,1.5SZ)      q bf16   }
  //  [1.5SZ,2SZ)     kb bf16  } -> g bf16 overlays [SZ,3SZ) for FFN
  //  [2SZ,2.5SZ)     vb bf16  }
  //  [3SZ,3.5SZ)     h2 bf16
  //  [3.5SZ,3.625SZ) idx int[BNT*16]
  //  [3.625SZ,..)    bf16 weights (~0.43 MB)
  const size_t SZ = (size_t)BNT * CC;
  float* wsf = (float*)d_ws;
  bf16_t* hb    = (bf16_t*)wsf;
  bf16_t* hnb   = (bf16_t*)(wsf + SZ / 2);
  bf16_t* hresb = hnb;
  bf16_t* qb    = (bf16_t*)(wsf + SZ);
  bf16_t* kb    = (bf16_t*)(wsf + SZ + SZ / 2);
  bf16_t* vb    = (bf16_t*)(wsf + 2 * SZ);
  bf16_t* g     = (bf16_t*)(wsf + SZ);
  bf16_t* h2    = (bf16_t*)(wsf + 3 * SZ);
  int*    idxw  = (int*)(wsf + 3 * SZ + SZ / 2);
  bf16_t* Wqb   = (bf16_t*)(idxw + (size_t)BNT * KNB);
  bf16_t* Wkb   = Wqb  + 16384;
  bf16_t* Wvb   = Wkb  + 16384;
  bf16_t* Wd2b  = Wvb  + 16384;
  bf16_t* Wab   = Wd2b + 16384;
  bf16_t* Wf1b  = Wab  + 16384;
  bf16_t* Wf2b  = Wf1b + 65536;

  inproj_compw_k<<<256 + 56, 256, 0, stream>>>(x, Win, bin, g1, b1, hb, hnb,
                                               Wq, Wk, Wv, Wd2, Wa, Wf1, Wf2,
                                               Wqb, Wkb, Wvb, Wd2b, Wab, Wf1b, Wf2b);
  knn_qkv_k<<<4096 + 1536, 256, 0, stream>>>(p, idxw, hnb, Wqb, Wkb, Wvb, qb, kb, vb);
  attn_k<<<BNT / 4, 256, 0, stream>>>(qb, kb, vb, p, idxw, Wd1, bd1, Wd2b, bd2, Wab, ba,
                                      g2, b2, hb, hresb, h2);
  gemm_k<1><<<dim3(BNT / 64, 8), 256, 0, stream>>>(h2, Wf1b, bf1, nullptr, g, nullptr, 4 * CC, CC);
  gemm_k<2><<<dim3(BNT / 64, 2), 256, 0, stream>>>(g, Wf2b, bf2, out, nullptr, hresb, CC, 4 * CC);
}

// Round 8
// 255.722 us; speedup vs baseline: 1.2219x; 1.0192x over previous
//
#include <hip/hip_runtime.h>

typedef __bf16 bf16_t;
typedef __bf16 bf16x8 __attribute__((ext_vector_type(8)));
typedef __bf16 bf16x2 __attribute__((ext_vector_type(2)));
typedef float  f32x4  __attribute__((ext_vector_type(4)));

#define MFMA16(a,b,c) __builtin_amdgcn_mfma_f32_16x16x32_bf16((a),(b),(c),0,0,0)

// ---- constants (problem is fixed-shape) ----
#define BB 8
#define NN 2048
#define CC 128
#define CIN 64
#define KNB 16            // neighbors
#define BNT (BB*NN)       // 16384 points

// XCD affinity: batch a block touches == blockIdx%8 == its XCD (R6-verified).
static __device__ __forceinline__ int remap256(int x) { return ((x & 7) << 5) | (x >> 3); }

static __device__ __forceinline__ bf16x8 cvt8(const float* src) {
  f32x4 a0 = *(const f32x4*)src;
  f32x4 a1 = *(const f32x4*)(src + 4);
  bf16x8 fr;
  fr[0] = (__bf16)a0[0]; fr[1] = (__bf16)a0[1]; fr[2] = (__bf16)a0[2]; fr[3] = (__bf16)a0[3];
  fr[4] = (__bf16)a1[0]; fr[5] = (__bf16)a1[1]; fr[6] = (__bf16)a1[2]; fr[7] = (__bf16)a1[3];
  return fr;
}

// ============================================================
// Kernel 1: in_proj + LN1 (R6-proven body; h stored bf16) with the
// weight-conversion blocks FUSED in (blocks 256..311, no LDS use).
// ============================================================
__global__ __launch_bounds__(256) void inproj_compw_k(
    const float* __restrict__ x, const float* __restrict__ Win, const float* __restrict__ bin,
    const float* __restrict__ g1, const float* __restrict__ b1,
    bf16_t* __restrict__ hb, bf16_t* __restrict__ hnb,
    const float* __restrict__ Wq, const float* __restrict__ Wk, const float* __restrict__ Wv,
    const float* __restrict__ Wd2, const float* __restrict__ Wa,
    const float* __restrict__ Wf1, const float* __restrict__ Wf2,
    bf16_t* __restrict__ Wqb, bf16_t* __restrict__ Wkb, bf16_t* __restrict__ Wvb,
    bf16_t* __restrict__ Wd2b, bf16_t* __restrict__ Wab,
    bf16_t* __restrict__ Wf1b, bf16_t* __restrict__ Wf2b) {
  __shared__ bf16_t As[64 * 72];
  __shared__ bf16_t Bs[128 * 72];
  __shared__ float hs[64 * 132];
  int t = threadIdx.x;
  if (blockIdx.x >= 256) {   // weight-conversion blocks (plain bf16 casts, RNE)
    int bi = blockIdx.x - 256;
    int mat = bi >> 3, xi = bi & 7;
    int nel = (mat >= 5) ? 65536 : 16384;
    const float* S = mat == 0 ? Wq : mat == 1 ? Wk : mat == 2 ? Wv : mat == 3 ? Wd2
                   : mat == 4 ? Wa : mat == 5 ? Wf1 : Wf2;
    bf16_t* D = mat == 0 ? Wqb : mat == 1 ? Wkb : mat == 2 ? Wvb : mat == 3 ? Wd2b
              : mat == 4 ? Wab : mat == 5 ? Wf1b : Wf2b;
    for (int i = xi * 256 + t; i * 8 < nel; i += 2048)
      *(bf16x8*)(D + i * 8) = cvt8(S + i * 8);
    return;
  }
  int lane = t & 63, w = t >> 6, quad = lane >> 4, l15 = lane & 15;
  int mBase = remap256(blockIdx.x) * 64;
  int b = mBase >> 11, n0 = mBase & (NN - 1);
  const float* xb = x + (size_t)b * CIN * NN;
  {
    int k = t >> 2, part = t & 3;
    #pragma unroll
    for (int i = 0; i < 4; ++i) {
      f32x4 v = *(const f32x4*)(xb + (size_t)k * NN + n0 + part * 16 + i * 4);
      #pragma unroll
      for (int j2 = 0; j2 < 4; ++j2) As[(part * 16 + i * 4 + j2) * 72 + k] = (__bf16)v[j2];
    }
  }
  {
    int row = t >> 1, seg = (t & 1) * 32;
    #pragma unroll
    for (int i = 0; i < 4; ++i)
      *(bf16x8*)(&Bs[row * 72 + seg + i * 8]) = cvt8(Win + (size_t)row * CIN + seg + i * 8);
  }
  __syncthreads();
  f32x4 acc[2][4] = {};
  #pragma unroll
  for (int s = 0; s < 2; ++s) {
    bf16x8 af[4];
    #pragma unroll
    for (int mt = 0; mt < 4; ++mt)
      af[mt] = *(const bf16x8*)(&As[(mt * 16 + l15) * 72 + s * 32 + quad * 8]);
    #pragma unroll
    for (int t2 = 0; t2 < 2; ++t2) {
      bf16x8 bfr = *(const bf16x8*)(&Bs[((w * 2 + t2) * 16 + l15) * 72 + s * 32 + quad * 8]);
      #pragma unroll
      for (int mt = 0; mt < 4; ++mt) acc[t2][mt] = MFMA16(af[mt], bfr, acc[t2][mt]);
    }
  }
  #pragma unroll
  for (int t2 = 0; t2 < 2; ++t2) {
    int col = (w * 2 + t2) * 16 + l15;
    float bv = bin[col];
    #pragma unroll
    for (int mt = 0; mt < 4; ++mt)
      #pragma unroll
      for (int reg = 0; reg < 4; ++reg)
        hs[(mt * 16 + quad * 4 + reg) * 132 + col] = acc[t2][mt][reg] + bv;
  }
  __syncthreads();
  {
    int row = t >> 2, c0 = (t & 3) * 32;
    float v[32];
    #pragma unroll
    for (int i = 0; i < 8; ++i) *(f32x4*)(v + i * 4) = *(const f32x4*)(&hs[row * 132 + c0 + i * 4]);
    float s1 = 0.f, s2 = 0.f;
    #pragma unroll
    for (int i = 0; i < 32; ++i) { s1 += v[i]; s2 += v[i] * v[i]; }
    s1 += __shfl_xor(s1, 1); s1 += __shfl_xor(s1, 2);
    s2 += __shfl_xor(s2, 1); s2 += __shfl_xor(s2, 2);
    float mu = s1 * (1.f / CC);
    float var = s2 * (1.f / CC) - mu * mu;
    float rs = rsqrtf(var + 1e-5f);
    bf16_t* hrow = hb + (size_t)(mBase + row) * CC + c0;
    #pragma unroll
    for (int i = 0; i < 4; ++i) {
      bf16x8 ho;
      #pragma unroll
      for (int j = 0; j < 8; ++j) ho[j] = (__bf16)v[i * 8 + j];
      *(bf16x8*)(hrow + i * 8) = ho;
    }
    bf16_t* hnrow = hnb + (size_t)(mBase + row) * CC + c0;
    #pragma unroll
    for (int i = 0; i < 4; ++i) {
      f32x4 g4a = ((const f32x4*)g1)[(c0 >> 2) + i * 2],     g4b = ((const f32x4*)g1)[(c0 >> 2) + i * 2 + 1];
      f32x4 b4a = ((const f32x4*)b1)[(c0 >> 2) + i * 2],     b4b = ((const f32x4*)b1)[(c0 >> 2) + i * 2 + 1];
      bf16x8 o;
      #pragma unroll
      for (int j = 0; j < 4; ++j) o[j]     = (__bf16)((v[i * 8 + j]     - mu) * rs * g4a[j] + b4a[j]);
      #pragma unroll
      for (int j = 0; j < 4; ++j) o[4 + j] = (__bf16)((v[i * 8 + 4 + j] - mu) * rs * g4b[j] + b4b[j]);
      *(bf16x8*)(hnrow + i * 8) = o;
    }
  }
}

// ============================================================
// KNN body (R6 verbatim, LDS passed in).
// ============================================================
static __device__ __forceinline__ void cas(double& a, double& b) {
  double lo = fmin(a, b), hi = fmax(a, b); a = lo; b = hi;
}
#define S8(K,o) \
  cas(K[o+0],K[o+1]); cas(K[o+2],K[o+3]); cas(K[o+4],K[o+5]); cas(K[o+6],K[o+7]); \
  cas(K[o+0],K[o+2]); cas(K[o+1],K[o+3]); cas(K[o+4],K[o+6]); cas(K[o+5],K[o+7]); \
  cas(K[o+1],K[o+2]); cas(K[o+5],K[o+6]); \
  cas(K[o+0],K[o+4]); cas(K[o+1],K[o+5]); cas(K[o+2],K[o+6]); cas(K[o+3],K[o+7]); \
  cas(K[o+2],K[o+4]); cas(K[o+3],K[o+5]); \
  cas(K[o+1],K[o+2]); cas(K[o+3],K[o+4]); cas(K[o+5],K[o+6]);
#define M8(K,a,b) \
  K[a+0]=fmin(K[a+0],K[b+7]); K[a+1]=fmin(K[a+1],K[b+6]); K[a+2]=fmin(K[a+2],K[b+5]); K[a+3]=fmin(K[a+3],K[b+4]); \
  K[a+4]=fmin(K[a+4],K[b+3]); K[a+5]=fmin(K[a+5],K[b+2]); K[a+6]=fmin(K[a+6],K[b+1]); K[a+7]=fmin(K[a+7],K[b+0]); \
  cas(K[a+0],K[a+4]); cas(K[a+1],K[a+5]); cas(K[a+2],K[a+6]); cas(K[a+3],K[a+7]); \
  cas(K[a+0],K[a+2]); cas(K[a+1],K[a+3]); cas(K[a+4],K[a+6]); cas(K[a+5],K[a+7]); \
  cas(K[a+0],K[a+1]); cas(K[a+2],K[a+3]); cas(K[a+4],K[a+5]); cas(K[a+6],K[a+7]);

static __device__ void knn_impl(float* sp, const float* __restrict__ p,
                                int* __restrict__ idxo, int bid) {
  float* px = sp; float* py = sp + NN; float* pz = sp + 2 * NN;
  int t = threadIdx.x;
  int b = bid >> 9;
  int g = bid & 511;
  const float* pb = p + (size_t)b * 3 * NN;
  for (int i = t; i < NN; i += 256) { px[i] = pb[i]; py[i] = pb[NN + i]; pz[i] = pb[2 * NN + i]; }
  __syncthreads();
  int w = t >> 6, lane = t & 63;
  int n = g * 4 + w;
  float pnx = px[n], pny = py[n], pnz = pz[n];
  double key[32];
  #pragma unroll
  for (int s = 0; s < 32; ++s) {
    int m = s * 64 + lane;
    float dx = pnx - px[m], dy = pny - py[m], dz = pnz - pz[m];
    float dist = dx * dx + dy * dy + dz * dz;
    unsigned db = (m == n) ? 0x7F800000u : __float_as_uint(dist);
    key[s] = __hiloint2double((int)db, m);
  }
  S8(key, 0); S8(key, 8); S8(key, 16); S8(key, 24);
  M8(key, 0, 8); M8(key, 16, 24); M8(key, 0, 16);
  const double DINF = __hiloint2double(0x7F900000, 0);
  int* myout = idxo + ((size_t)b * NN + n) * KNB;
  #pragma unroll 1
  for (int r = 0; r < 16; ++r) {
    double gm = key[0];
    #pragma unroll
    for (int off = 1; off < 64; off <<= 1) {
      double o = __shfl_xor(gm, off);
      gm = fmin(gm, o);
    }
    if (lane == 0) myout[r] = __double2loint(gm);
    bool win = (key[0] == gm);
    key[0] = win ? key[1] : key[0];
    key[1] = win ? key[2] : key[1];
    key[2] = win ? key[3] : key[2];
    key[3] = win ? key[4] : key[3];
    key[4] = win ? key[5] : key[4];
    key[5] = win ? key[6] : key[5];
    key[6] = win ? key[7] : key[6];
    key[7] = win ? DINF   : key[7];
  }
}

// ============================================================
// 64x64 GEMM body, BK=32, A & W bf16 (pre-converted).
// EPI: 1 relu->bf16, 2 +resid(bf16) transposed fp32 [B,C,N], 3 bf16.
// ============================================================
template<int EPI>
static __device__ void gemm_body(bf16_t* As, bf16_t* Bs,
    const bf16_t* __restrict__ Ab, const bf16_t* __restrict__ Wb, const float* __restrict__ bias,
    float* __restrict__ outF, bf16_t* __restrict__ outB, const bf16_t* __restrict__ resid,
    int mBase, int nBase, int Ncol, int Kdim) {
  int t = threadIdx.x;
  int lane = t & 63, w = t >> 6, quad = lane >> 4, l15 = lane & 15;
  int r = t >> 2, seg = (t & 3) * 8;
  f32x4 acc[4] = {{0,0,0,0},{0,0,0,0},{0,0,0,0},{0,0,0,0}};
  for (int k0 = 0; k0 < Kdim; k0 += 32) {
    __syncthreads();
    *(bf16x8*)(&As[r * 40 + seg]) = *(const bf16x8*)(Ab + (size_t)(mBase + r) * Kdim + k0 + seg);
    *(bf16x8*)(&Bs[r * 40 + seg]) = *(const bf16x8*)(Wb + (size_t)(nBase + r) * Kdim + k0 + seg);
    __syncthreads();
    bf16x8 bfr = *(const bf16x8*)(&Bs[(w * 16 + l15) * 40 + quad * 8]);
    #pragma unroll
    for (int mt = 0; mt < 4; ++mt) {
      bf16x8 afr = *(const bf16x8*)(&As[(mt * 16 + l15) * 40 + quad * 8]);
      acc[mt] = MFMA16(afr, bfr, acc[mt]);
    }
  }
  int n = nBase + w * 16 + l15;
  float bv = bias ? bias[n] : 0.f;
  #pragma unroll
  for (int mt = 0; mt < 4; ++mt) {
    #pragma unroll
    for (int reg = 0; reg < 4; ++reg) {
      int m = mBase + mt * 16 + quad * 4 + reg;
      float val = acc[mt][reg] + bv;
      if (EPI == 1) {
        outB[(size_t)m * Ncol + n] = (__bf16)fmaxf(val, 0.f);
      } else if (EPI == 3) {
        outB[(size_t)m * Ncol + n] = (__bf16)val;
      } else {
        val += (float)resid[(size_t)m * CC + n];
        int bo = m >> 11, np = m & (NN - 1);
        outF[((size_t)bo * CC + n) * NN + np] = val;
      }
    }
  }
}

template<int EPI>
__global__ __launch_bounds__(256) void gemm_k(
    const bf16_t* __restrict__ Ab, const bf16_t* __restrict__ Wb, const float* __restrict__ bias,
    float* __restrict__ outF, bf16_t* __restrict__ outB, const bf16_t* __restrict__ resid,
    int Ncol, int Kdim) {
  __shared__ bf16_t As[64 * 40];
  __shared__ bf16_t Bs[64 * 40];
  gemm_body<EPI>(As, Bs, Ab, Wb, bias, outF, outB, resid,
                 remap256(blockIdx.x) * 64, blockIdx.y * 64, Ncol, Kdim);
}

// ============================================================
// Fused knn + qkv dispatch (R11/R13-proven). q = hn@Wq^T, k = hn@Wk^T,
// v = hn@Wv^T — all bf16 (R0 numerics; NO Wa-fold).
// ============================================================
__global__ __launch_bounds__(256) void knn_qkv_k(
    const float* __restrict__ p, int* __restrict__ idxo,
    const bf16_t* __restrict__ hnb,
    const bf16_t* __restrict__ Wqb, const bf16_t* __restrict__ Wkb, const bf16_t* __restrict__ Wvb,
    bf16_t* __restrict__ qb, bf16_t* __restrict__ kb, bf16_t* __restrict__ vb) {
  __shared__ __align__(16) char smem[3 * NN * 4];   // 24576 B
  if (blockIdx.x < 4096) {
    knn_impl((float*)smem, p, idxo, blockIdx.x);
  } else {
    bf16_t* As = (bf16_t*)smem;
    bf16_t* Bs = As + 64 * 40;
    int bx = blockIdx.x - 4096;
    int yy = bx >> 8, xx = bx & 255;
    int sel = yy >> 1;
    int mB = remap256(xx) * 64, nB = (yy & 1) * 64;
    if (sel == 0)      gemm_body<3>(As, Bs, hnb, Wqb, nullptr, nullptr, qb, nullptr, mB, nB, CC, CC);
    else if (sel == 1) gemm_body<3>(As, Bs, hnb, Wkb, nullptr, nullptr, kb, nullptr, mB, nB, CC, CC);
    else               gemm_body<3>(As, Bs, hnb, Wvb, nullptr, nullptr, vb, nullptr, mB, nB, CC, CC);
  }
}

// ============================================================
// Kernel 5: fused neighbor attention — R7 FP graph EXACTLY.
// Changes vs R7 (address/barrier only, values identical):
//   (1) u and ts SHARE one LDS buffer (u dead after pass D; +1 barrier)
//       -> LDS 40.4KB -> ~23KB, removes the 3-block/CU residency cap.
//   (2) wd1s padded index (c + 2*(c>>5)): the four (t&3) read groups
//       land on banks {0,8,16,24} -> conflict-free (was 32 reads x 4-way).
// ============================================================
__global__ __launch_bounds__(256, 3) void attn_k(
    const bf16_t* __restrict__ qbuf, const bf16_t* __restrict__ kbuf, const bf16_t* __restrict__ vbuf,
    const float* __restrict__ p, const int* __restrict__ idx,
    const float* __restrict__ Wd1, const float* __restrict__ bd1,
    const bf16_t* __restrict__ Wd2b, const float* __restrict__ bd2,
    const bf16_t* __restrict__ Wab, const float* __restrict__ ba,
    const float* __restrict__ g2, const float* __restrict__ b2,
    const bf16_t* __restrict__ hb, bf16_t* __restrict__ hresb, bf16_t* __restrict__ h2) {
  __shared__ bf16_t ts[64 * 136];      // holds u, then q-k+d (shared buffer)
  __shared__ float hrs[4 * 128];
  __shared__ f32x4 wd1s[134];          // padded: idx = c + 2*(c>>5)
  __shared__ f32x4 rels4[64];          // {rx,ry,rz,0}
  __shared__ int idxs[64];             // pre-scaled: (batch*NN+jj)*CC
  int t = threadIdx.x;
  int lane = t & 63, w = t >> 6, quad = lane >> 4, l15 = lane & 15;
  int batch = blockIdx.x & 7, grp = blockIdx.x >> 3;
  int bn0 = batch * NN + grp * 4;
  const float* pb = p + (size_t)batch * 3 * NN;
  int col0 = w * 32 + l15;
  int col1 = col0 + 16;

  if (t < 64) {
    int jj = idx[(size_t)bn0 * KNB + t];
    idxs[t] = (batch * NN + jj) * CC;
    int npt = grp * 4 + (t >> 4);
    f32x4 rv;
    rv[0] = pb[npt]          - pb[jj];
    rv[1] = pb[NN + npt]     - pb[NN + jj];
    rv[2] = pb[2 * NN + npt] - pb[2 * NN + jj];
    rv[3] = 0.f;
    rels4[t] = rv;
  }
  if (t < 128) {
    f32x4 wv;
    wv[0] = Wd1[t * 3]; wv[1] = Wd1[t * 3 + 1]; wv[2] = Wd1[t * 3 + 2]; wv[3] = bd1[t];
    wd1s[t + 2 * (t >> 5)] = wv;
  }
  __syncthreads();

  // cooperative u: each thread computes one row-quarter (32 channels);
  // same fmaf chain + bf16 rounding as R7 -> bit-identical values.
  {
    int row = t >> 2, cseg = (t & 3) * 32;
    f32x4 rv = rels4[row];
    #pragma unroll
    for (int i = 0; i < 4; ++i) {
      bf16x8 u8;
      #pragma unroll
      for (int j = 0; j < 8; ++j) {
        int c = cseg + i * 8 + j;
        f32x4 wv = wd1s[c + 2 * (c >> 5)];
        float tv = fmaf(wv[0], rv[0], fmaf(wv[1], rv[1], fmaf(wv[2], rv[2], wv[3])));
        u8[j] = (__bf16)fmaxf(tv, 0.f);
      }
      *(bf16x8*)(&ts[row * 136 + cseg + i * 8]) = u8;
    }
  }
  __syncthreads();

  // q/k gathers issued before pass-D MFMAs (latency hides under MFMA)
  float qv[2][4];
  #pragma unroll
  for (int mt = 0; mt < 4; ++mt) {
    qv[0][mt] = (float)qbuf[(size_t)(bn0 + mt) * CC + col0];
    qv[1][mt] = (float)qbuf[(size_t)(bn0 + mt) * CC + col1];
  }
  float kreg[2][4][4];
  #pragma unroll
  for (int mt = 0; mt < 4; ++mt)
    #pragma unroll
    for (int reg = 0; reg < 4; ++reg) {
      size_t base = (size_t)idxs[mt * 16 + quad * 4 + reg];
      kreg[0][mt][reg] = (float)kbuf[base + col0];
      kreg[1][mt][reg] = (float)kbuf[base + col1];
    }

  // pass D: accd = u @ Wd2^T (u fragments read from the shared buffer)
  f32x4 accd[2][4] = {};
  {
    bf16x8 Bd[2][4];
    #pragma unroll
    for (int t2 = 0; t2 < 2; ++t2) {
      int row = w * 32 + t2 * 16 + l15;
      #pragma unroll
      for (int s = 0; s < 4; ++s)
        Bd[t2][s] = *(const bf16x8*)(Wd2b + (size_t)row * CC + s * 32 + quad * 8);
    }
    #pragma unroll
    for (int s = 0; s < 4; ++s) {
      bf16x8 af[4];
      #pragma unroll
      for (int mt = 0; mt < 4; ++mt)
        af[mt] = *(const bf16x8*)(&ts[(mt * 16 + l15) * 136 + s * 32 + quad * 8]);
      #pragma unroll
      for (int t2 = 0; t2 < 2; ++t2)
        #pragma unroll
        for (int mt = 0; mt < 4; ++mt)
          accd[t2][mt] = MFMA16(af[mt], Bd[t2][s], accd[t2][mt]);
    }
  }

  __syncthreads();   // all u reads complete -> safe to overwrite ts

  // ts = q - k + d  (R0/R7 formula verbatim; accd keeps the biased d)
  {
    float b2v0 = bd2[col0], b2v1 = bd2[col1];
    #pragma unroll
    for (int mt = 0; mt < 4; ++mt)
      #pragma unroll
      for (int reg = 0; reg < 4; ++reg) {
        int row = mt * 16 + quad * 4 + reg;
        float d0 = accd[0][mt][reg] + b2v0;
        float d1 = accd[1][mt][reg] + b2v1;
        accd[0][mt][reg] = d0;
        accd[1][mt][reg] = d1;
        ts[row * 136 + col0] = (__bf16)(qv[0][mt] - kreg[0][mt][reg] + d0);
        ts[row * 136 + col1] = (__bf16)(qv[1][mt] - kreg[1][mt][reg] + d1);
      }
  }

  // v/h gathers issued here — latency hides under barrier + Ba loads
  float vreg[2][4][4];
  #pragma unroll
  for (int mt = 0; mt < 4; ++mt)
    #pragma unroll
    for (int reg = 0; reg < 4; ++reg) {
      size_t base = (size_t)idxs[mt * 16 + quad * 4 + reg];
      vreg[0][mt][reg] = (float)vbuf[base + col0];
      vreg[1][mt][reg] = (float)vbuf[base + col1];
    }
  float hv[2][4];
  if (quad == 0) {
    #pragma unroll
    for (int mt = 0; mt < 4; ++mt) {
      hv[0][mt] = (float)hb[(size_t)(bn0 + mt) * CC + col0];
      hv[1][mt] = (float)hb[(size_t)(bn0 + mt) * CC + col1];
    }
  }
  __syncthreads();

  // logits MFMA: accl = ts @ Wa^T
  bf16x8 Ba[2][4];
  #pragma unroll
  for (int t2 = 0; t2 < 2; ++t2) {
    int row = w * 32 + t2 * 16 + l15;
    #pragma unroll
    for (int s = 0; s < 4; ++s)
      Ba[t2][s] = *(const bf16x8*)(Wab + (size_t)row * CC + s * 32 + quad * 8);
  }
  f32x4 accl[2][4] = {};
  #pragma unroll
  for (int s = 0; s < 4; ++s) {
    bf16x8 af[4];
    #pragma unroll
    for (int mt = 0; mt < 4; ++mt)
      af[mt] = *(const bf16x8*)(&ts[(mt * 16 + l15) * 136 + s * 32 + quad * 8]);
    #pragma unroll
    for (int t2 = 0; t2 < 2; ++t2)
      #pragma unroll
      for (int mt = 0; mt < 4; ++mt)
        accl[t2][mt] = MFMA16(af[mt], Ba[t2][s], accl[t2][mt]);
  }

  // softmax over neighbors + weighted sum (R0 verbatim)
  #pragma unroll
  for (int t2 = 0; t2 < 2; ++t2) {
    int col = t2 ? col1 : col0;
    float bav = ba[col];
    #pragma unroll
    for (int mt = 0; mt < 4; ++mt) {
      float lv0 = accl[t2][mt][0] + bav, lv1 = accl[t2][mt][1] + bav;
      float lv2 = accl[t2][mt][2] + bav, lv3 = accl[t2][mt][3] + bav;
      float mx = fmaxf(fmaxf(lv0, lv1), fmaxf(lv2, lv3));
      mx = fmaxf(mx, __shfl_xor(mx, 16));
      mx = fmaxf(mx, __shfl_xor(mx, 32));
      float e0 = __expf(lv0 - mx), e1 = __expf(lv1 - mx);
      float e2 = __expf(lv2 - mx), e3 = __expf(lv3 - mx);
      float ss = e0 + e1 + e2 + e3;
      ss += __shfl_xor(ss, 16); ss += __shfl_xor(ss, 32);
      float yv = e0 * (vreg[t2][mt][0] + accd[t2][mt][0])
               + e1 * (vreg[t2][mt][1] + accd[t2][mt][1])
               + e2 * (vreg[t2][mt][2] + accd[t2][mt][2])
               + e3 * (vreg[t2][mt][3] + accd[t2][mt][3]);
      yv += __shfl_xor(yv, 16); yv += __shfl_xor(yv, 32);
      if (quad == 0) {
        float hvv = hv[t2][mt] + yv / ss;
        hresb[(size_t)(bn0 + mt) * CC + col] = (__bf16)hvv;
        hrs[mt * 128 + col] = hvv;
      }
    }
  }
  __syncthreads();

  {
    int c0 = lane * 2;
    float v0 = hrs[w * 128 + c0], v1 = hrs[w * 128 + c0 + 1];
    float s1 = v0 + v1, s2 = v0 * v0 + v1 * v1;
    #pragma unroll
    for (int off = 1; off < 64; off <<= 1) { s1 += __shfl_xor(s1, off); s2 += __shfl_xor(s2, off); }
    float mu = s1 * (1.f / CC);
    float var = s2 * (1.f / CC) - mu * mu;
    float rs = rsqrtf(var + 1e-5f);
    bf16x2 o;
    o[0] = (__bf16)((v0 - mu) * rs * g2[c0] + b2[c0]);
    o[1] = (__bf16)((v1 - mu) * rs * g2[c0 + 1] + b2[c0 + 1]);
    *(bf16x2*)(h2 + (size_t)(bn0 + w) * CC + c0) = o;
  }
}

// ============================================================
extern "C" void kernel_launch(void* const* d_in, const int* in_sizes, int n_in,
                              void* d_out, int out_size, void* d_ws, size_t ws_size,
                              hipStream_t stream) {
  const float* x   = (const float*)d_in[0];
  const float* p   = (const float*)d_in[1];
  const float* Win = (const float*)d_in[2];
  const float* bin = (const float*)d_in[3];
  const float* Wq  = (const float*)d_in[4];
  const float* Wk  = (const float*)d_in[5];
  const float* Wv  = (const float*)d_in[6];
  const float* Wd1 = (const float*)d_in[7];
  const float* bd1 = (const float*)d_in[8];
  const float* Wd2 = (const float*)d_in[9];
  const float* bd2 = (const float*)d_in[10];
  const float* Wa  = (const float*)d_in[11];
  const float* ba  = (const float*)d_in[12];
  const float* g1  = (const float*)d_in[13];
  const float* b1  = (const float*)d_in[14];
  const float* g2  = (const float*)d_in[15];
  const float* b2  = (const float*)d_in[16];
  const float* Wf1 = (const float*)d_in[17];
  const float* bf1 = (const float*)d_in[18];
  const float* Wf2 = (const float*)d_in[19];
  const float* bf2 = (const float*)d_in[20];
  float* out = (float*)d_out;

  // workspace (float offsets; SZ = BNT*CC = 2,097,152) — R0 layout:
  //  [0,SZ/2)        h bf16 (residual 1)
  //  [SZ/2,SZ)       hnb bf16 -> hres bf16 overlay (attn out, ffn2 resid)
  //  [SZ,1.5SZ)      q bf16   }
  //  [1.5SZ,2SZ)     kb bf16  } -> g bf16 overlays [SZ,3SZ) for FFN
  //  [2SZ,2.5SZ)     vb bf16  }
  //  [3SZ,3.5SZ)     h2 bf16
  //  [3.5SZ,3.625SZ) idx int[BNT*16]
  //  [3.625SZ,..)    bf16 weights (~0.43 MB)
  const size_t SZ = (size_t)BNT * CC;
  float* wsf = (float*)d_ws;
  bf16_t* hb    = (bf16_t*)wsf;
  bf16_t* hnb   = (bf16_t*)(wsf + SZ / 2);
  bf16_t* hresb = hnb;
  bf16_t* qb    = (bf16_t*)(wsf + SZ);
  bf16_t* kb    = (bf16_t*)(wsf + SZ + SZ / 2);
  bf16_t* vb    = (bf16_t*)(wsf + 2 * SZ);
  bf16_t* g     = (bf16_t*)(wsf + SZ);
  bf16_t* h2    = (bf16_t*)(wsf + 3 * SZ);
  int*    idxw  = (int*)(wsf + 3 * SZ + SZ / 2);
  bf16_t* Wqb   = (bf16_t*)(idxw + (size_t)BNT * KNB);
  bf16_t* Wkb   = Wqb  + 16384;
  bf16_t* Wvb   = Wkb  + 16384;
  bf16_t* Wd2b  = Wvb  + 16384;
  bf16_t* Wab   = Wd2b + 16384;
  bf16_t* Wf1b  = Wab  + 16384;
  bf16_t* Wf2b  = Wf1b + 65536;

  inproj_compw_k<<<256 + 56, 256, 0, stream>>>(x, Win, bin, g1, b1, hb, hnb,
                                               Wq, Wk, Wv, Wd2, Wa, Wf1, Wf2,
                                               Wqb, Wkb, Wvb, Wd2b, Wab, Wf1b, Wf2b);
  knn_qkv_k<<<4096 + 1536, 256, 0, stream>>>(p, idxw, hnb, Wqb, Wkb, Wvb, qb, kb, vb);
  attn_k<<<BNT / 4, 256, 0, stream>>>(qb, kb, vb, p, idxw, Wd1, bd1, Wd2b, bd2, Wab, ba,
                                      g2, b2, hb, hresb, h2);
  gemm_k<1><<<dim3(BNT / 64, 8), 256, 0, stream>>>(h2, Wf1b, bf1, nullptr, g, nullptr, 4 * CC, CC);
  gemm_k<2><<<dim3(BNT / 64, 2), 256, 0, stream>>>(g, Wf2b, bf2, out, nullptr, hresb, CC, 4 * CC);
}